// Round 1
// baseline (14157.660 us; speedup 1.0000x reference)
//
#include <hip/hip_runtime.h>

// Seq2SeqLSTM: B=32, T=128, E=512, H=1024, V=32000
// Pipeline per launch:
//   cvt weights->bf16 (x5), gather embeddings (x2), zero states,
//   4x { proj GEMM (bf16 MFMA) ; 128x lstm_step (fp32) },
//   output GEMM (bf16 MFMA) -> d_out logits, in-place log_softmax.

#define TSEQ  128
#define NB    32
#define EMB   512
#define HID   1024
#define G4    4096
#define VOC   32000
#define ROWS  (TSEQ * NB)   /* 4096 */

typedef __attribute__((ext_vector_type(8))) short short8;   // 8 bf16 (4 VGPRs)
typedef __attribute__((ext_vector_type(4))) float f32x4;    // MFMA acc

__device__ __forceinline__ unsigned short f2bf(float f) {
  unsigned u = __builtin_bit_cast(unsigned, f);
  u += 0x7FFFu + ((u >> 16) & 1u);            // RNE
  return (unsigned short)(u >> 16);
}

__device__ __forceinline__ void async16(const void* g, void* l) {
  __builtin_amdgcn_global_load_lds((const __attribute__((address_space(1))) void*)g,
                                   (__attribute__((address_space(3))) void*)l, 16, 0, 0);
}

// ---------------- fp32 -> bf16 bulk convert ----------------
__global__ __launch_bounds__(256) void cvt_bf16(const float* __restrict__ src,
                                                unsigned short* __restrict__ dst, int n) {
  int i = (blockIdx.x * 256 + threadIdx.x) * 8;
  if (i >= n) return;
  float4 a = *(const float4*)&src[i];
  float4 b = *(const float4*)&src[i + 4];
  ushort4 o0 = make_ushort4(f2bf(a.x), f2bf(a.y), f2bf(a.z), f2bf(a.w));
  ushort4 o1 = make_ushort4(f2bf(b.x), f2bf(b.y), f2bf(b.z), f2bf(b.w));
  *(ushort4*)&dst[i] = o0;
  *(ushort4*)&dst[i + 4] = o1;
}

// ---------------- embedding gather -> bf16 [T*B, E] (row = t*B+b) ----------------
__global__ __launch_bounds__(256) void gather_embed(const int* __restrict__ tok,
                                                    const float* __restrict__ emb,
                                                    unsigned short* __restrict__ dst, int dec) {
  int idx = blockIdx.x * 256 + threadIdx.x;   // one float4 per thread over [4096][512]
  int n = idx >> 7;                           // row (EMB/4 = 128 chunks per row)
  int e = (idx & 127) * 4;
  int t = n >> 5, b = n & 31;
  int token;
  if (dec) token = (t == 0) ? 0 : tok[b * TSEQ + t - 1];
  else     token = tok[b * TSEQ + t];
  float4 v = *(const float4*)&emb[(size_t)token * EMB + e];
  ushort4 o = make_ushort4(f2bf(v.x), f2bf(v.y), f2bf(v.z), f2bf(v.w));
  *(ushort4*)&dst[(size_t)n * EMB + e] = o;
}

// ---------------- zero fill ----------------
__global__ __launch_bounds__(256) void zero_f(float* __restrict__ p, int n4) {
  // n4 = number of float4s
  for (int i = blockIdx.x * 256 + threadIdx.x; i < n4; i += gridDim.x * 256)
    ((float4*)p)[i] = make_float4(0.f, 0.f, 0.f, 0.f);
}

// ---------------- bf16 MFMA GEMM: C[M,N] = A[M,K] * B[N,K]^T + bias[N] ----------------
// mode 0: C[row*N+col]   (proj -> x_gates)
// mode 1: C[(b*TSEQ+t)*N+col], row = t*NB+b  (logits scatter to [B,T,V])
__global__ __launch_bounds__(256)
void gemm_bt(const unsigned short* __restrict__ A, const unsigned short* __restrict__ B,
             float* __restrict__ C, const float* __restrict__ bias,
             int M, int N, int K, int mode) {
  __shared__ short As[128 * 32];
  __shared__ short Bs[128 * 32];
  const int tid  = threadIdx.x;
  const int lane = tid & 63;
  const int wave = tid >> 6;
  const int m0 = blockIdx.y * 128, n0 = blockIdx.x * 128;
  const int wm = (wave >> 1) * 64, wn = (wave & 1) * 64;
  const int r = lane & 15, q = lane >> 4;

  f32x4 acc[4][4];
#pragma unroll
  for (int i = 0; i < 4; ++i)
#pragma unroll
    for (int j = 0; j < 4; ++j) acc[i][j] = (f32x4){0.f, 0.f, 0.f, 0.f};

  const int srow = tid >> 2;         // 0..63
  const int scol = (tid & 3) * 8;    // 0,8,16,24

  for (int k0 = 0; k0 < K; k0 += 32) {
    // stage 128x32 bf16 tiles of A and B; LDS dest = wave-uniform base + lane*16
    async16(&A[(size_t)(m0 + srow) * K + k0 + scol],      &As[tid * 8]);
    async16(&A[(size_t)(m0 + 64 + srow) * K + k0 + scol], &As[2048 + tid * 8]);
    async16(&B[(size_t)(n0 + srow) * K + k0 + scol],      &Bs[tid * 8]);
    async16(&B[(size_t)(n0 + 64 + srow) * K + k0 + scol], &Bs[2048 + tid * 8]);
    __builtin_amdgcn_s_waitcnt(0);   // drain vmcnt before barrier (belt & braces)
    __syncthreads();

    short8 af[4], bfr[4];
#pragma unroll
    for (int tm = 0; tm < 4; ++tm)
      af[tm] = *(const short8*)&As[(wm + tm * 16 + r) * 32 + q * 8];
#pragma unroll
    for (int tn = 0; tn < 4; ++tn)
      bfr[tn] = *(const short8*)&Bs[(wn + tn * 16 + r) * 32 + q * 8];
#pragma unroll
    for (int tm = 0; tm < 4; ++tm)
#pragma unroll
      for (int tn = 0; tn < 4; ++tn)
        acc[tm][tn] = __builtin_amdgcn_mfma_f32_16x16x32_bf16(af[tm], bfr[tn], acc[tm][tn], 0, 0, 0);
    __syncthreads();
  }

#pragma unroll
  for (int tm = 0; tm < 4; ++tm) {
#pragma unroll
    for (int tn = 0; tn < 4; ++tn) {
      f32x4 v = acc[tm][tn];
      int col = n0 + wn + tn * 16 + r;          // C/D: col = lane&15
      float bv = bias[col];
#pragma unroll
      for (int e = 0; e < 4; ++e) {
        int row = m0 + wm + tm * 16 + q * 4 + e; // C/D: row = quad*4 + reg
        float val = v[e] + bv;
        size_t oidx;
        if (mode == 0) {
          oidx = (size_t)row * N + col;
        } else {
          int tt = row >> 5, bb = row & 31;      // row = t*NB + b
          oidx = (size_t)(bb * TSEQ + tt) * N + col;
        }
        C[oidx] = val;
      }
    }
  }
}

// ---------------- fused LSTM step: gates = xg + h_in @ Whh^T ; cell ; h_out ----------------
// grid = 256 blocks; block j owns h-dims [j*4, j*4+4) across all 4 gates (16 Whh rows).
#define KT 128
__global__ __launch_bounds__(256)
void lstm_step(const float* __restrict__ Whh, const float* __restrict__ xg,
               const float* __restrict__ hin, float* __restrict__ hout,
               float* __restrict__ c, unsigned short* __restrict__ hseq) {
  __shared__ float ht[NB][KT + 4];
  __shared__ float gl[NB][16];
  const int tid = threadIdx.x;
  const int b = tid & 31;
  const int rp = tid >> 5;                 // 0..7 -> local rows 2rp, 2rp+1
  const int d0 = blockIdx.x * 4;
  const int l0 = rp * 2, l1 = rp * 2 + 1;  // local row = gate*4 + (hd-d0)
  const int row0 = (l0 >> 2) * HID + d0 + (l0 & 3);
  const int row1 = (l1 >> 2) * HID + d0 + (l1 & 3);
  float a0 = xg[b * G4 + row0];
  float a1 = xg[b * G4 + row1];
  const int ldb = tid >> 3;                // 0..31
  const int ldc = (tid & 7) * 16;          // 0..112

  for (int kt = 0; kt < HID; kt += KT) {
    __syncthreads();
    *(float4*)&ht[ldb][ldc]      = *(const float4*)&hin[ldb * HID + kt + ldc];
    *(float4*)&ht[ldb][ldc + 4]  = *(const float4*)&hin[ldb * HID + kt + ldc + 4];
    *(float4*)&ht[ldb][ldc + 8]  = *(const float4*)&hin[ldb * HID + kt + ldc + 8];
    *(float4*)&ht[ldb][ldc + 12] = *(const float4*)&hin[ldb * HID + kt + ldc + 12];
    __syncthreads();
    const float* w0 = &Whh[(size_t)row0 * HID + kt];
    const float* w1 = &Whh[(size_t)row1 * HID + kt];
#pragma unroll 8
    for (int k = 0; k < KT; k += 4) {
      float4 hv = *(const float4*)&ht[b][k];
      float4 wa = *(const float4*)&w0[k];
      float4 wb = *(const float4*)&w1[k];
      a0 += hv.x * wa.x + hv.y * wa.y + hv.z * wa.z + hv.w * wa.w;
      a1 += hv.x * wb.x + hv.y * wb.y + hv.z * wb.z + hv.w * wb.w;
    }
  }
  gl[b][l0] = a0;
  gl[b][l1] = a1;
  __syncthreads();
  if (tid < 128) {
    int bb = tid & 31, u = tid >> 5;       // u = 0..3
    int hd = d0 + u;
    float iv = gl[bb][0 + u], fv = gl[bb][4 + u], gv = gl[bb][8 + u], ov = gl[bb][12 + u];
    float ig = 1.f / (1.f + __expf(-iv));
    float fg = 1.f / (1.f + __expf(-fv));
    float gg = tanhf(gv);
    float og = 1.f / (1.f + __expf(-ov));
    float cn = fg * c[bb * HID + hd] + ig * gg;
    float hn = og * tanhf(cn);
    c[bb * HID + hd] = cn;
    hout[bb * HID + hd] = hn;
    hseq[bb * HID + hd] = f2bf(hn);
  }
}

// ---------------- in-place log_softmax over V per row ----------------
__global__ __launch_bounds__(256) void logsoftmax_rows(float* __restrict__ out) {
  __shared__ float red[256];
  float* p = out + (size_t)blockIdx.x * VOC;
  const int tid = threadIdx.x;
  float m = -3.4e38f;
  for (int i = tid; i < VOC / 4; i += 256) {
    float4 v = ((const float4*)p)[i];
    m = fmaxf(m, fmaxf(fmaxf(v.x, v.y), fmaxf(v.z, v.w)));
  }
  red[tid] = m; __syncthreads();
  for (int s = 128; s; s >>= 1) { if (tid < s) red[tid] = fmaxf(red[tid], red[tid + s]); __syncthreads(); }
  float M = red[0]; __syncthreads();
  float sum = 0.f;
  for (int i = tid; i < VOC / 4; i += 256) {
    float4 v = ((const float4*)p)[i];
    sum += __expf(v.x - M) + __expf(v.y - M) + __expf(v.z - M) + __expf(v.w - M);
  }
  red[tid] = sum; __syncthreads();
  for (int s = 128; s; s >>= 1) { if (tid < s) red[tid] += red[tid + s]; __syncthreads(); }
  float L = M + logf(red[0]); __syncthreads();
  for (int i = tid; i < VOC / 4; i += 256) {
    float4 v = ((const float4*)p)[i];
    v.x -= L; v.y -= L; v.z -= L; v.w -= L;
    ((float4*)p)[i] = v;
  }
}

extern "C" void kernel_launch(void* const* d_in, const int* in_sizes, int n_in,
                              void* d_out, int out_size, void* d_ws, size_t ws_size,
                              hipStream_t stream) {
  const int*   x     = (const int*)  d_in[0];
  const int*   tgt   = (const int*)  d_in[1];
  const float* emb   = (const float*)d_in[2];
  const float* eWih0 = (const float*)d_in[3];
  const float* eWhh0 = (const float*)d_in[4];
  const float* eb0   = (const float*)d_in[5];
  const float* eWih1 = (const float*)d_in[6];
  const float* eWhh1 = (const float*)d_in[7];
  const float* eb1   = (const float*)d_in[8];
  const float* dWih0 = (const float*)d_in[9];
  const float* dWhh0 = (const float*)d_in[10];
  const float* db0   = (const float*)d_in[11];
  const float* dWih1 = (const float*)d_in[12];
  const float* dWhh1 = (const float*)d_in[13];
  const float* db1   = (const float*)d_in[14];
  const float* fcW   = (const float*)d_in[15];
  const float* fcb   = (const float*)d_in[16];
  float* out = (float*)d_out;

  // workspace carve (~184 MB)
  char* base = (char*)d_ws;
  size_t off = 0;
  auto carve = [&](size_t bytes) -> void* {
    void* p = base + off;
    off += (bytes + 255) & ~(size_t)255;
    return p;
  };
  unsigned short* wE0   = (unsigned short*)carve((size_t)G4 * EMB * 2);
  unsigned short* wE1   = (unsigned short*)carve((size_t)G4 * HID * 2);
  unsigned short* wD0   = (unsigned short*)carve((size_t)G4 * EMB * 2);
  unsigned short* wD1   = (unsigned short*)carve((size_t)G4 * HID * 2);
  unsigned short* wFC   = (unsigned short*)carve((size_t)VOC * HID * 2);
  unsigned short* encin = (unsigned short*)carve((size_t)ROWS * EMB * 2);
  unsigned short* decin = (unsigned short*)carve((size_t)ROWS * EMB * 2);
  unsigned short* seqA  = (unsigned short*)carve((size_t)ROWS * HID * 2);
  unsigned short* seqB  = (unsigned short*)carve((size_t)ROWS * HID * 2);
  float* xg     = (float*)carve((size_t)ROWS * G4 * 4);
  float* states = (float*)carve((size_t)6 * NB * HID * 4);
  float* hA0 = states;
  float* hB0 = states + 1 * NB * HID;
  float* c0  = states + 2 * NB * HID;
  float* hA1 = states + 3 * NB * HID;
  float* hB1 = states + 4 * NB * HID;
  float* c1  = states + 5 * NB * HID;

  // weights -> bf16
  cvt_bf16<<<dim3(G4 * EMB / 2048), 256, 0, stream>>>(eWih0, wE0, G4 * EMB);
  cvt_bf16<<<dim3(G4 * HID / 2048), 256, 0, stream>>>(eWih1, wE1, G4 * HID);
  cvt_bf16<<<dim3(G4 * EMB / 2048), 256, 0, stream>>>(dWih0, wD0, G4 * EMB);
  cvt_bf16<<<dim3(G4 * HID / 2048), 256, 0, stream>>>(dWih1, wD1, G4 * HID);
  cvt_bf16<<<dim3(VOC * HID / 2048), 256, 0, stream>>>(fcW, wFC, VOC * HID);
  // embeddings
  gather_embed<<<dim3(ROWS * EMB / 1024), 256, 0, stream>>>(x, emb, encin, 0);
  gather_embed<<<dim3(ROWS * EMB / 1024), 256, 0, stream>>>(tgt, emb, decin, 1);
  // zero h/c states
  zero_f<<<dim3(192), 256, 0, stream>>>(states, 6 * NB * HID / 4);

  // ---- encoder layer 0 ----
  gemm_bt<<<dim3(G4 / 128, ROWS / 128), 256, 0, stream>>>(encin, wE0, xg, eb0, ROWS, G4, EMB, 0);
  for (int t = 0; t < TSEQ; ++t) {
    const float* hi = (t & 1) ? hB0 : hA0;
    float*       ho = (t & 1) ? hA0 : hB0;
    lstm_step<<<dim3(256), 256, 0, stream>>>(eWhh0, xg + (size_t)t * NB * G4, hi, ho, c0,
                                             seqA + (size_t)t * NB * HID);
  }
  // ---- encoder layer 1 ----
  gemm_bt<<<dim3(G4 / 128, ROWS / 128), 256, 0, stream>>>(seqA, wE1, xg, eb1, ROWS, G4, HID, 0);
  for (int t = 0; t < TSEQ; ++t) {
    const float* hi = (t & 1) ? hB1 : hA1;
    float*       ho = (t & 1) ? hA1 : hB1;
    lstm_step<<<dim3(256), 256, 0, stream>>>(eWhh1, xg + (size_t)t * NB * G4, hi, ho, c1,
                                             seqB + (size_t)t * NB * HID);
  }
  // ---- decoder layer 0 (states continue from encoder finals, held in hA0/c0) ----
  gemm_bt<<<dim3(G4 / 128, ROWS / 128), 256, 0, stream>>>(decin, wD0, xg, db0, ROWS, G4, EMB, 0);
  for (int t = 0; t < TSEQ; ++t) {
    const float* hi = (t & 1) ? hB0 : hA0;
    float*       ho = (t & 1) ? hA0 : hB0;
    lstm_step<<<dim3(256), 256, 0, stream>>>(dWhh0, xg + (size_t)t * NB * G4, hi, ho, c0,
                                             seqA + (size_t)t * NB * HID);
  }
  // ---- decoder layer 1 ----
  gemm_bt<<<dim3(G4 / 128, ROWS / 128), 256, 0, stream>>>(seqA, wD1, xg, db1, ROWS, G4, HID, 0);
  for (int t = 0; t < TSEQ; ++t) {
    const float* hi = (t & 1) ? hB1 : hA1;
    float*       ho = (t & 1) ? hA1 : hB1;
    lstm_step<<<dim3(256), 256, 0, stream>>>(dWhh1, xg + (size_t)t * NB * G4, hi, ho, c1,
                                             seqB + (size_t)t * NB * HID);
  }
  // ---- logits + log_softmax ----
  gemm_bt<<<dim3(VOC / 128, ROWS / 128), 256, 0, stream>>>(seqB, wFC, out, fcb, ROWS, VOC, HID, 1);
  logsoftmax_rows<<<dim3(ROWS), 256, 0, stream>>>(out);
}

// Round 2
// 8858.724 us; speedup vs baseline: 1.5982x; 1.5982x over previous
//
#include <hip/hip_runtime.h>

// Seq2SeqLSTM: B=32, T=128, E=512, H=1024, V=32000
// R1: replace 512 lstm_step launches with 4 persistent lstm_scan kernels
// (Whh bf16 in VGPRs, MFMA recurrence, device-scope grid barrier per step).

#define TSEQ  128
#define NB    32
#define EMB   512
#define HID   1024
#define G4    4096
#define VOC   32000
#define ROWS  (TSEQ * NB)   /* 4096 */
#define SCAN_BLOCKS 128

typedef __attribute__((ext_vector_type(8))) short short8;   // 8 bf16 (4 VGPRs)
typedef __attribute__((ext_vector_type(4))) float f32x4;    // MFMA acc

__device__ __forceinline__ unsigned short f2bf(float f) {
  unsigned u = __builtin_bit_cast(unsigned, f);
  u += 0x7FFFu + ((u >> 16) & 1u);            // RNE
  return (unsigned short)(u >> 16);
}

__device__ __forceinline__ short8 pack8(float4 a, float4 b) {
  short8 v;
  v[0] = (short)f2bf(a.x); v[1] = (short)f2bf(a.y);
  v[2] = (short)f2bf(a.z); v[3] = (short)f2bf(a.w);
  v[4] = (short)f2bf(b.x); v[5] = (short)f2bf(b.y);
  v[6] = (short)f2bf(b.z); v[7] = (short)f2bf(b.w);
  return v;
}

__device__ __forceinline__ float fsig(float x)  { return 1.f / (1.f + __expf(-x)); }
__device__ __forceinline__ float ftanh(float x) { return 1.f - 2.f / (1.f + __expf(2.f * x)); }

__device__ __forceinline__ void async16(const void* g, void* l) {
  __builtin_amdgcn_global_load_lds((const __attribute__((address_space(1))) void*)g,
                                   (__attribute__((address_space(3))) void*)l, 16, 0, 0);
}

// ---------------- fp32 -> bf16 bulk convert ----------------
__global__ __launch_bounds__(256) void cvt_bf16(const float* __restrict__ src,
                                                unsigned short* __restrict__ dst, int n) {
  int i = (blockIdx.x * 256 + threadIdx.x) * 8;
  if (i >= n) return;
  float4 a = *(const float4*)&src[i];
  float4 b = *(const float4*)&src[i + 4];
  *(ushort4*)&dst[i]     = make_ushort4(f2bf(a.x), f2bf(a.y), f2bf(a.z), f2bf(a.w));
  *(ushort4*)&dst[i + 4] = make_ushort4(f2bf(b.x), f2bf(b.y), f2bf(b.z), f2bf(b.w));
}

// ---------------- embedding gather -> bf16 [T*B, E] (row = t*B+b) ----------------
__global__ __launch_bounds__(256) void gather_embed(const int* __restrict__ tok,
                                                    const float* __restrict__ emb,
                                                    unsigned short* __restrict__ dst, int dec) {
  int idx = blockIdx.x * 256 + threadIdx.x;   // one float4 per thread over [4096][512]
  int n = idx >> 7;                           // row (EMB/4 = 128 chunks per row)
  int e = (idx & 127) * 4;
  int t = n >> 5, b = n & 31;
  int token;
  if (dec) token = (t == 0) ? 0 : tok[b * TSEQ + t - 1];
  else     token = tok[b * TSEQ + t];
  float4 v = *(const float4*)&emb[(size_t)token * EMB + e];
  *(ushort4*)&dst[(size_t)n * EMB + e] = make_ushort4(f2bf(v.x), f2bf(v.y), f2bf(v.z), f2bf(v.w));
}

// ---------------- zero fill ----------------
__global__ __launch_bounds__(256) void zero_f(float* __restrict__ p, int n4) {
  for (int i = blockIdx.x * 256 + threadIdx.x; i < n4; i += gridDim.x * 256)
    ((float4*)p)[i] = make_float4(0.f, 0.f, 0.f, 0.f);
}

// ---------------- bf16 MFMA GEMM: C[M,N] = A[M,K] * B[N,K]^T + bias[N] ----------------
// mode 0: C[row*N+col]   (proj -> x_gates)
// mode 1: C[(b*TSEQ+t)*N+col], row = t*NB+b  (logits scatter to [B,T,V])
__global__ __launch_bounds__(256)
void gemm_bt(const unsigned short* __restrict__ A, const unsigned short* __restrict__ B,
             float* __restrict__ C, const float* __restrict__ bias,
             int M, int N, int K, int mode) {
  __shared__ short As[128 * 32];
  __shared__ short Bs[128 * 32];
  const int tid  = threadIdx.x;
  const int lane = tid & 63;
  const int wave = tid >> 6;
  const int m0 = blockIdx.y * 128, n0 = blockIdx.x * 128;
  const int wm = (wave >> 1) * 64, wn = (wave & 1) * 64;
  const int r = lane & 15, q = lane >> 4;

  f32x4 acc[4][4];
#pragma unroll
  for (int i = 0; i < 4; ++i)
#pragma unroll
    for (int j = 0; j < 4; ++j) acc[i][j] = (f32x4){0.f, 0.f, 0.f, 0.f};

  const int srow = tid >> 2;         // 0..63
  const int scol = (tid & 3) * 8;    // 0,8,16,24

  for (int k0 = 0; k0 < K; k0 += 32) {
    async16(&A[(size_t)(m0 + srow) * K + k0 + scol],      &As[tid * 8]);
    async16(&A[(size_t)(m0 + 64 + srow) * K + k0 + scol], &As[2048 + tid * 8]);
    async16(&B[(size_t)(n0 + srow) * K + k0 + scol],      &Bs[tid * 8]);
    async16(&B[(size_t)(n0 + 64 + srow) * K + k0 + scol], &Bs[2048 + tid * 8]);
    __builtin_amdgcn_s_waitcnt(0);
    __syncthreads();

    short8 af[4], bfr[4];
#pragma unroll
    for (int tm = 0; tm < 4; ++tm)
      af[tm] = *(const short8*)&As[(wm + tm * 16 + r) * 32 + q * 8];
#pragma unroll
    for (int tn = 0; tn < 4; ++tn)
      bfr[tn] = *(const short8*)&Bs[(wn + tn * 16 + r) * 32 + q * 8];
#pragma unroll
    for (int tm = 0; tm < 4; ++tm)
#pragma unroll
      for (int tn = 0; tn < 4; ++tn)
        acc[tm][tn] = __builtin_amdgcn_mfma_f32_16x16x32_bf16(af[tm], bfr[tn], acc[tm][tn], 0, 0, 0);
    __syncthreads();
  }

#pragma unroll
  for (int tm = 0; tm < 4; ++tm) {
#pragma unroll
    for (int tn = 0; tn < 4; ++tn) {
      f32x4 v = acc[tm][tn];
      int col = n0 + wn + tn * 16 + r;
      float bv = bias[col];
#pragma unroll
      for (int e = 0; e < 4; ++e) {
        int row = m0 + wm + tm * 16 + q * 4 + e;
        float val = v[e] + bv;
        size_t oidx;
        if (mode == 0) {
          oidx = (size_t)row * N + col;
        } else {
          int tt = row >> 5, bb = row & 31;
          oidx = (size_t)(bb * TSEQ + tt) * N + col;
        }
        C[oidx] = val;
      }
    }
  }
}

// ---------------- persistent LSTM layer scan ----------------
// 128 blocks x 256 threads (4 waves). Block j owns h-dims [j*8, j*8+8) ->
// 32 gate rows. Whh slice (bf16) lives in VGPRs for the whole 128-step scan.
// Wave w computes output tile (mt=w>>1 batch-half, nt=w&1 gate-row-half),
// full K=1024, no cross-wave reduction. Grid barrier per timestep.
__global__ __launch_bounds__(256, 1)
void lstm_scan(const float* __restrict__ Whh, const float* __restrict__ xg,
               unsigned short* __restrict__ hA, unsigned short* __restrict__ hB,
               float* __restrict__ cbuf, unsigned short* __restrict__ hseq,
               unsigned* __restrict__ bar) {
  __shared__ float Gs[32][33];
  const int tid  = threadIdx.x;
  const int lane = tid & 63;
  const int wave = tid >> 6;
  const int r = lane & 15, q = lane >> 4;
  const int mt = wave >> 1, nt = wave & 1;
  const int D0 = blockIdx.x * 8;

  // --- preload Whh B-fragments into registers (bf16), 16 rows x 1024 K per wave
  const int lr   = nt * 16 + r;                         // local gate-row 0..31
  const int grow = (lr >> 3) * HID + D0 + (lr & 7);     // global gate-row
  short8 Bf[32];
  {
    const float* wp = &Whh[(size_t)grow * HID];
#pragma unroll
    for (int ks = 0; ks < 32; ++ks) {
      float4 w0 = *(const float4*)&wp[ks * 32 + q * 8];
      float4 w1 = *(const float4*)&wp[ks * 32 + q * 8 + 4];
      Bf[ks] = pack8(w0, w1);
    }
  }

  // --- cell state in register: thread -> (b = tid>>3, d = tid&7)
  const int cd = tid & 7, cb = tid >> 3;
  float creg = cbuf[cb * HID + D0 + cd];

  for (int t = 0; t < TSEQ; ++t) {
    const unsigned short* hin  = (t & 1) ? hB : hA;
    unsigned short*       hout = (t & 1) ? hA : hB;

    // --- G tile = h_prev @ Whh_slice^T  (A-frags from global bf16 h)
    const unsigned short* hrow = &hin[(size_t)(mt * 16 + r) * HID + q * 8];
    f32x4 a0 = (f32x4){0.f,0.f,0.f,0.f}, a1 = a0, a2 = a0, a3 = a0;
#pragma unroll
    for (int ks = 0; ks < 32; ks += 4) {
      a0 = __builtin_amdgcn_mfma_f32_16x16x32_bf16(*(const short8*)&hrow[(ks+0)*32], Bf[ks+0], a0, 0, 0, 0);
      a1 = __builtin_amdgcn_mfma_f32_16x16x32_bf16(*(const short8*)&hrow[(ks+1)*32], Bf[ks+1], a1, 0, 0, 0);
      a2 = __builtin_amdgcn_mfma_f32_16x16x32_bf16(*(const short8*)&hrow[(ks+2)*32], Bf[ks+2], a2, 0, 0, 0);
      a3 = __builtin_amdgcn_mfma_f32_16x16x32_bf16(*(const short8*)&hrow[(ks+3)*32], Bf[ks+3], a3, 0, 0, 0);
    }
    f32x4 acc = (a0 + a1) + (a2 + a3);
    // D layout: m(batch) = q*4+e, n(local row) = r
#pragma unroll
    for (int e = 0; e < 4; ++e)
      Gs[mt * 16 + q * 4 + e][nt * 16 + r] = acc[e];
    __syncthreads();

    // --- cell update for (cb, cd)
    const float* xrow = &xg[((size_t)t * NB + cb) * G4 + D0 + cd];
    float iv = Gs[cb][cd]      + xrow[0];
    float fv = Gs[cb][8 + cd]  + xrow[HID];
    float gv = Gs[cb][16 + cd] + xrow[2 * HID];
    float ov = Gs[cb][24 + cd] + xrow[3 * HID];
    float ig = fsig(iv), fg = fsig(fv), og = fsig(ov);
    float gg = ftanh(gv);
    creg = fg * creg + ig * gg;
    float hn = og * ftanh(creg);
    unsigned short hb = f2bf(hn);
    hout[cb * HID + D0 + cd] = hb;
    hseq[((size_t)t * NB + cb) * HID + D0 + cd] = hb;

    // --- device-scope grid barrier (release h writes, acquire others')
    __syncthreads();
    if (tid == 0) {
      __threadfence();
      atomicAdd(bar, 1u);
      const unsigned target = (unsigned)(t + 1) * SCAN_BLOCKS;
      while (__hip_atomic_load(bar, __ATOMIC_RELAXED, __HIP_MEMORY_SCOPE_AGENT) < target)
        __builtin_amdgcn_s_sleep(2);
      __threadfence();
    }
    __syncthreads();
  }
  cbuf[cb * HID + D0 + cd] = creg;   // final c (decoder init / unused for dec)
}

// ---------------- in-place log_softmax over V per row ----------------
__global__ __launch_bounds__(256) void logsoftmax_rows(float* __restrict__ out) {
  __shared__ float red[256];
  float* p = out + (size_t)blockIdx.x * VOC;
  const int tid = threadIdx.x;
  float m = -3.4e38f;
  for (int i = tid; i < VOC / 4; i += 256) {
    float4 v = ((const float4*)p)[i];
    m = fmaxf(m, fmaxf(fmaxf(v.x, v.y), fmaxf(v.z, v.w)));
  }
  red[tid] = m; __syncthreads();
  for (int s = 128; s; s >>= 1) { if (tid < s) red[tid] = fmaxf(red[tid], red[tid + s]); __syncthreads(); }
  float M = red[0]; __syncthreads();
  float sum = 0.f;
  for (int i = tid; i < VOC / 4; i += 256) {
    float4 v = ((const float4*)p)[i];
    sum += __expf(v.x - M) + __expf(v.y - M) + __expf(v.z - M) + __expf(v.w - M);
  }
  red[tid] = sum; __syncthreads();
  for (int s = 128; s; s >>= 1) { if (tid < s) red[tid] += red[tid + s]; __syncthreads(); }
  float L = M + logf(red[0]); __syncthreads();
  for (int i = tid; i < VOC / 4; i += 256) {
    float4 v = ((const float4*)p)[i];
    v.x -= L; v.y -= L; v.z -= L; v.w -= L;
    ((float4*)p)[i] = v;
  }
}

extern "C" void kernel_launch(void* const* d_in, const int* in_sizes, int n_in,
                              void* d_out, int out_size, void* d_ws, size_t ws_size,
                              hipStream_t stream) {
  const int*   x     = (const int*)  d_in[0];
  const int*   tgt   = (const int*)  d_in[1];
  const float* emb   = (const float*)d_in[2];
  const float* eWih0 = (const float*)d_in[3];
  const float* eWhh0 = (const float*)d_in[4];
  const float* eb0   = (const float*)d_in[5];
  const float* eWih1 = (const float*)d_in[6];
  const float* eWhh1 = (const float*)d_in[7];
  const float* eb1   = (const float*)d_in[8];
  const float* dWih0 = (const float*)d_in[9];
  const float* dWhh0 = (const float*)d_in[10];
  const float* db0   = (const float*)d_in[11];
  const float* dWih1 = (const float*)d_in[12];
  const float* dWhh1 = (const float*)d_in[13];
  const float* db1   = (const float*)d_in[14];
  const float* fcW   = (const float*)d_in[15];
  const float* fcb   = (const float*)d_in[16];
  float* out = (float*)d_out;

  char* base = (char*)d_ws;
  size_t off = 0;
  auto carve = [&](size_t bytes) -> void* {
    void* p = base + off;
    off += (bytes + 255) & ~(size_t)255;
    return p;
  };
  unsigned short* wE0   = (unsigned short*)carve((size_t)G4 * EMB * 2);
  unsigned short* wE1   = (unsigned short*)carve((size_t)G4 * HID * 2);
  unsigned short* wD0   = (unsigned short*)carve((size_t)G4 * EMB * 2);
  unsigned short* wD1   = (unsigned short*)carve((size_t)G4 * HID * 2);
  unsigned short* wFC   = (unsigned short*)carve((size_t)VOC * HID * 2);
  unsigned short* encin = (unsigned short*)carve((size_t)ROWS * EMB * 2);
  unsigned short* decin = (unsigned short*)carve((size_t)ROWS * EMB * 2);
  unsigned short* seqA  = (unsigned short*)carve((size_t)ROWS * HID * 2);
  unsigned short* seqB  = (unsigned short*)carve((size_t)ROWS * HID * 2);
  float* xg = (float*)carve((size_t)ROWS * G4 * 4);
  // zero-region (contiguous, all sizes multiple of 256B):
  unsigned short* hA0 = (unsigned short*)carve((size_t)NB * HID * 2);
  unsigned short* hB0 = (unsigned short*)carve((size_t)NB * HID * 2);
  unsigned short* hA1 = (unsigned short*)carve((size_t)NB * HID * 2);
  unsigned short* hB1 = (unsigned short*)carve((size_t)NB * HID * 2);
  float* c0 = (float*)carve((size_t)NB * HID * 4);
  float* c1 = (float*)carve((size_t)NB * HID * 4);
  unsigned* bars = (unsigned*)carve(1024);
  const int zero_n4 = (4 * NB * HID * 2 + 2 * NB * HID * 4 + 1024) / 16;

  // weights -> bf16
  cvt_bf16<<<dim3(G4 * EMB / 2048), 256, 0, stream>>>(eWih0, wE0, G4 * EMB);
  cvt_bf16<<<dim3(G4 * HID / 2048), 256, 0, stream>>>(eWih1, wE1, G4 * HID);
  cvt_bf16<<<dim3(G4 * EMB / 2048), 256, 0, stream>>>(dWih0, wD0, G4 * EMB);
  cvt_bf16<<<dim3(G4 * HID / 2048), 256, 0, stream>>>(dWih1, wD1, G4 * HID);
  cvt_bf16<<<dim3(VOC * HID / 2048), 256, 0, stream>>>(fcW, wFC, VOC * HID);
  // embeddings
  gather_embed<<<dim3(ROWS * EMB / 1024), 256, 0, stream>>>(x, emb, encin, 0);
  gather_embed<<<dim3(ROWS * EMB / 1024), 256, 0, stream>>>(tgt, emb, decin, 1);
  // zero h/c/barrier region
  zero_f<<<dim3(128), 256, 0, stream>>>((float*)hA0, zero_n4);

  // ---- encoder layer 0 ----
  gemm_bt<<<dim3(G4 / 128, ROWS / 128), 256, 0, stream>>>(encin, wE0, xg, eb0, ROWS, G4, EMB, 0);
  lstm_scan<<<dim3(SCAN_BLOCKS), 256, 0, stream>>>(eWhh0, xg, hA0, hB0, c0, seqA, bars + 0);
  // ---- encoder layer 1 ----
  gemm_bt<<<dim3(G4 / 128, ROWS / 128), 256, 0, stream>>>(seqA, wE1, xg, eb1, ROWS, G4, HID, 0);
  lstm_scan<<<dim3(SCAN_BLOCKS), 256, 0, stream>>>(eWhh1, xg, hA1, hB1, c1, seqB, bars + 16);
  // ---- decoder layer 0 (h/c continue from encoder finals: final h in slot A, c in cbuf) ----
  gemm_bt<<<dim3(G4 / 128, ROWS / 128), 256, 0, stream>>>(decin, wD0, xg, db0, ROWS, G4, EMB, 0);
  lstm_scan<<<dim3(SCAN_BLOCKS), 256, 0, stream>>>(dWhh0, xg, hA0, hB0, c0, seqA, bars + 32);
  // ---- decoder layer 1 ----
  gemm_bt<<<dim3(G4 / 128, ROWS / 128), 256, 0, stream>>>(seqA, wD1, xg, db1, ROWS, G4, HID, 0);
  lstm_scan<<<dim3(SCAN_BLOCKS), 256, 0, stream>>>(dWhh1, xg, hA1, hB1, c1, seqB, bars + 48);
  // ---- logits + log_softmax ----
  gemm_bt<<<dim3(VOC / 128, ROWS / 128), 256, 0, stream>>>(seqB, wFC, out, fcb, ROWS, VOC, HID, 1);
  logsoftmax_rows<<<dim3(ROWS), 256, 0, stream>>>(out);
}